// Round 11
// baseline (182.092 us; speedup 1.0000x reference)
//
#include <hip/hip_runtime.h>

typedef _Float16 half_t;
typedef _Float16 half8  __attribute__((ext_vector_type(8)));
typedef _Float16 half4v __attribute__((ext_vector_type(4)));
typedef float    f32x16 __attribute__((ext_vector_type(16)));
typedef float    f32x4  __attribute__((ext_vector_type(4)));

#define DEVI static __device__ __forceinline__

constexpr int B_  = 16384;
constexpr int T_  = 28;
constexpr int IN_ = 28;
constexpr int H_  = 128;
constexpr int C_  = 11;
constexpr int BT  = 64;    // batch rows per block; grid = 256 = 1 block/CU
constexpr int NT  = 768;   // 12 waves: 4x L0, 4x L1, 4x L2 (R8 shapes, proven no-spill)
constexpr int HSTR = 136;  // LDS stride (halves): 272B rows; b128 start-bank advance 4 = balanced
constexpr int XSTR = 40;

constexpr int HBUF = BT * HSTR;
constexpr int XBUF = BT * XSTR;
constexpr int SM_HALVES = 6 * HBUF + 2 * XBUF;  // h[3][2] + xin[2]
constexpr size_t SM_BYTES = (size_t)SM_HALVES * 2 + 3 * H_ * 4;  // + bias = 116224 B

DEVI f32x16 mfma(half8 a, half8 b, f32x16 c) {
  return __builtin_amdgcn_mfma_f32_32x32x16_f16(a, b, c, 0, 0, 0);
}

DEVI half8 frag(const half_t* base, int kc) { return *(const half8*)(base + kc * 16); }

// A-fragments, one 32-row m-tile of a 128x128 row-major fp32 matrix.
// A layout (32x32x16 f16, validated R2-R10): lane holds A[m=lane&31][k=(lane>>5)*8+j].
DEVI void loadw8(half8 d[8], const float* __restrict__ w, int mrow, int hf) {
  const float* p = w + mrow * H_ + hf * 8;
#pragma unroll
  for (int kc = 0; kc < 8; ++kc) {
    half8 f;
#pragma unroll
    for (int j = 0; j < 8; ++j) f[j] = (half_t)p[kc * 16 + j];
    d[kc] = f;
  }
}

// h = relu(e + o + bias) -> hout.  C/D layout (HW-verified m74/m101):
// col = lane&31 (batch), row = (reg&3)+8*(reg>>2)+4*(lane>>5).
DEVI void epi2(half_t* __restrict__ hout, const float* __restrict__ bl,
               f32x16 e, f32x16 o, int mrow0, int ncol0, int l31, int hf) {
#pragma unroll
  for (int rq = 0; rq < 4; ++rq) {
    const int n0 = mrow0 + rq * 8 + hf * 4;
    const f32x4 b4 = *(const f32x4*)&bl[n0];
    half4v h4;
#pragma unroll
    for (int ri = 0; ri < 4; ++ri)
      h4[ri] = (half_t)fmaxf(e[rq * 4 + ri] + o[rq * 4 + ri] + b4[ri], 0.0f);
    *(half4v*)&hout[(ncol0 + l31) * HSTR + n0] = h4;
  }
}

// 16 k-chunks (wi then wh), 2 n-tiles, 4 independent MFMA chains (even/odd kc):
// dependent-MFMA gap = 3 issue slots (~96 cyc) -> hides dep latency.
DEVI void mm16x4(const half_t* bi0, const half_t* bi1,
                 const half_t* br0, const half_t* br1,
                 const half8 wi[8], const half8 wh[8],
                 f32x16& e0, f32x16& o0, f32x16& e1, f32x16& o1) {
  f32x16 ae0 = {}, ao0 = {}, ae1 = {}, ao1 = {};
#pragma unroll
  for (int kc = 0; kc < 8; kc += 2) {
    ae0 = mfma(wi[kc],     frag(bi0, kc),     ae0);
    ae1 = mfma(wi[kc],     frag(bi1, kc),     ae1);
    ao0 = mfma(wi[kc + 1], frag(bi0, kc + 1), ao0);
    ao1 = mfma(wi[kc + 1], frag(bi1, kc + 1), ao1);
  }
#pragma unroll
  for (int kc = 0; kc < 8; kc += 2) {
    ae0 = mfma(wh[kc],     frag(br0, kc),     ae0);
    ae1 = mfma(wh[kc],     frag(br1, kc),     ae1);
    ao0 = mfma(wh[kc + 1], frag(br0, kc + 1), ao0);
    ao1 = mfma(wh[kc + 1], frag(br1, kc + 1), ao1);
  }
  e0 = ae0; o0 = ao0; e1 = ae1; o1 = ao1;
}

__global__ __launch_bounds__(NT) __attribute__((amdgpu_waves_per_eu(3)))
void rnn_pipe(const float* __restrict__ x,
              const float* __restrict__ wih0, const float* __restrict__ whh0,
              const float* __restrict__ bih0, const float* __restrict__ bhh0,
              const float* __restrict__ wih1, const float* __restrict__ whh1,
              const float* __restrict__ bih1, const float* __restrict__ bhh1,
              const float* __restrict__ wih2, const float* __restrict__ whh2,
              const float* __restrict__ bih2, const float* __restrict__ bhh2,
              const float* __restrict__ fcw, const float* __restrict__ fcb,
              float* __restrict__ out)
{
  extern __shared__ __align__(16) char smraw[];
  half_t* hs   = (half_t*)smraw;
  float*  bias = (float*)(hs + SM_HALVES);
#define HB(l, b) (hs + ((l) * 2 + (b)) * HBUF)
#define XB(b)    (hs + 6 * HBUF + (b) * XBUF)

  const int tid  = threadIdx.x;
  const int b0   = blockIdx.x * BT;
  const int lane = tid & 63;
  const int wid  = tid >> 6;
  const int l31  = lane & 31;
  const int hf   = lane >> 5;

  // ---- init: zero all LDS buffers (h_{-1}=0, x pad cols=0), stage biases ----
  for (int i = tid; i < SM_HALVES / 2; i += NT) ((unsigned int*)hs)[i] = 0u;
  if (tid < H_) {
    bias[tid]          = bih0[tid] + bhh0[tid];
    bias[H_ + tid]     = bih1[tid] + bhh1[tid];
    bias[2 * H_ + tid] = bih2[tid] + bhh2[tid];
  }
  __syncthreads();
  if (tid < 512) {  // stage x[t=0] into XB(0)
    const int row = tid >> 3, ch = tid & 7;
    if (ch < 7) {
      const f32x4 v = *(const f32x4*)(x + (size_t)(b0 + row) * (T_ * IN_) + ch * 4);
      half4v h4;
#pragma unroll
      for (int j = 0; j < 4; ++j) h4[j] = (half_t)v[j];
      *(half4v*)&XB(0)[row * XSTR + ch * 4] = h4;
    }
  }
  __syncthreads();

  // ===== wave-specialized pipeline: iter i computes h0[i], h1[i-1], h2[i-2] =====
  // Reads hit parity p, writes parity np: ONE barrier/iter; 30 barriers per branch.
  if (wid < 4) {
    // ---- L0: 1 m-tile, 2 n-tiles; also stages x[t=i+1] (tids 0..255) ----
    const int mt = wid;
    half8 ai0[2], ah0[8];
    loadw8(ah0, whh0, mt * 32 + l31, hf);
#pragma unroll
    for (int kc = 0; kc < 2; ++kc) {  // wih0: K=28 padded to 32 with zeros
      half8 f;
#pragma unroll
      for (int j = 0; j < 8; ++j) {
        const int k = kc * 16 + hf * 8 + j;
        f[j] = (k < IN_) ? (half_t)wih0[(mt * 32 + l31) * IN_ + k] : (half_t)0.0f;
      }
      ai0[kc] = f;
    }
    const int xrow = tid >> 3, xch = tid & 7;  // tid<256: rows 0..31 (+32 second chunk)
    for (int i = 0; i < T_ + 2; ++i) {
      const int p = i & 1, np = p ^ 1;
      const bool xact = (xch < 7) && (i + 1 < T_);
      f32x4 xq0, xq1;
      if (xact) {  // issue global loads early; consumed at iteration end
        const float* xp = x + (size_t)(i + 1) * IN_ + xch * 4;
        xq0 = *(const f32x4*)(xp + (size_t)(b0 + xrow) * (T_ * IN_));
        xq1 = *(const f32x4*)(xp + (size_t)(b0 + xrow + 32) * (T_ * IN_));
      }
      if (i < T_) {
        const half_t* bx0 = XB(p) + l31 * XSTR + hf * 8;
        const half_t* bx1 = XB(p) + (32 + l31) * XSTR + hf * 8;
        const half_t* bh0 = HB(0, p) + l31 * HSTR + hf * 8;
        const half_t* bh1 = HB(0, p) + (32 + l31) * HSTR + hf * 8;
        // 4 chains: x-chunk0 -> e, x-chunk1 -> o, then h kc even->e / odd->o
        f32x16 e0 = {}, o0 = {}, e1 = {}, o1 = {};
        e0 = mfma(ai0[0], frag(bx0, 0), e0);
        e1 = mfma(ai0[0], frag(bx1, 0), e1);
        o0 = mfma(ai0[1], frag(bx0, 1), o0);
        o1 = mfma(ai0[1], frag(bx1, 1), o1);
#pragma unroll
        for (int kc = 0; kc < 8; kc += 2) {
          e0 = mfma(ah0[kc],     frag(bh0, kc),     e0);
          e1 = mfma(ah0[kc],     frag(bh1, kc),     e1);
          o0 = mfma(ah0[kc + 1], frag(bh0, kc + 1), o0);
          o1 = mfma(ah0[kc + 1], frag(bh1, kc + 1), o1);
        }
        epi2(HB(0, np), bias, e0, o0, mt * 32, 0,  l31, hf);
        epi2(HB(0, np), bias, e1, o1, mt * 32, 32, l31, hf);
      }
      if (xact) {
        half4v h4a, h4b;
#pragma unroll
        for (int j = 0; j < 4; ++j) { h4a[j] = (half_t)xq0[j]; h4b[j] = (half_t)xq1[j]; }
        *(half4v*)&XB(np)[xrow * XSTR + xch * 4] = h4a;
        *(half4v*)&XB(np)[(xrow + 32) * XSTR + xch * 4] = h4b;
      }
      __syncthreads();
    }
  } else if (wid < 8) {
    // ---- L1: 1 m-tile, 2 n-tiles, 4-chain inner loop ----
    const int mt1 = wid - 4;
    half8 wi[8], wh[8];
    loadw8(wi, wih1, mt1 * 32 + l31, hf);
    loadw8(wh, whh1, mt1 * 32 + l31, hf);
    for (int i = 0; i < T_ + 2; ++i) {
      const int p = i & 1, np = p ^ 1;
      if (i >= 1 && i < T_ + 1) {
        const half_t* bi0 = HB(0, p) + l31 * HSTR + hf * 8;        // h0[t=i-1]
        const half_t* bi1 = HB(0, p) + (32 + l31) * HSTR + hf * 8;
        const half_t* br0 = HB(1, p) + l31 * HSTR + hf * 8;        // h1[t=i-2]
        const half_t* br1 = HB(1, p) + (32 + l31) * HSTR + hf * 8;
        f32x16 e0, o0, e1, o1;
        mm16x4(bi0, bi1, br0, br1, wi, wh, e0, o0, e1, o1);
        epi2(HB(1, np), bias + H_, e0, o0, mt1 * 32, 0,  l31, hf);
        epi2(HB(1, np), bias + H_, e1, o1, mt1 * 32, 32, l31, hf);
      }
      __syncthreads();
    }
  } else {
    // ---- L2: 1 m-tile, 2 n-tiles, 4-chain inner loop ----
    const int mt2 = wid - 8;
    half8 wi[8], wh[8];
    loadw8(wi, wih2, mt2 * 32 + l31, hf);
    loadw8(wh, whh2, mt2 * 32 + l31, hf);
    for (int i = 0; i < T_ + 2; ++i) {
      const int p = i & 1, np = p ^ 1;
      if (i >= 2) {
        const half_t* bi0 = HB(1, p) + l31 * HSTR + hf * 8;        // h1[t=i-2]
        const half_t* bi1 = HB(1, p) + (32 + l31) * HSTR + hf * 8;
        const half_t* br0 = HB(2, p) + l31 * HSTR + hf * 8;        // h2[t=i-3]
        const half_t* br1 = HB(2, p) + (32 + l31) * HSTR + hf * 8;
        f32x16 e0, o0, e1, o1;
        mm16x4(bi0, bi1, br0, br1, wi, wh, e0, o0, e1, o1);
        epi2(HB(2, np), bias + 2 * H_, e0, o0, mt2 * 32, 0,  l31, hf);
        epi2(HB(2, np), bias + 2 * H_, e1, o1, mt2 * 32, 32, l31, hf);
      }
      __syncthreads();
    }
  }
  // last in-loop barrier (i=29) makes final h2 (parity 0) visible

  // ---- FC head: out[b][c] = h2_last[b] . fcw[c] + fcb[c] ----
  if (tid < 512) {
    const half_t* h2f = HB(2, 0);
    const int row = tid >> 3, q = tid & 7;
    for (int c = q; c < C_; c += 8) {
      float s = fcb[c];
      const float* wp = fcw + c * H_;
#pragma unroll
      for (int k = 0; k < H_; k += 8) {
        const half8 hv = *(const half8*)&h2f[row * HSTR + k];
#pragma unroll
        for (int j = 0; j < 8; ++j) s += (float)hv[j] * wp[k + j];
      }
      out[(size_t)(b0 + row) * C_ + c] = s;
    }
  }
#undef HB
#undef XB
}

extern "C" void kernel_launch(void* const* d_in, const int* in_sizes, int n_in,
                              void* d_out, int out_size, void* d_ws, size_t ws_size,
                              hipStream_t stream)
{
  const float* x    = (const float*)d_in[0];
  const float* wih0 = (const float*)d_in[1];
  const float* whh0 = (const float*)d_in[2];
  const float* bih0 = (const float*)d_in[3];
  const float* bhh0 = (const float*)d_in[4];
  const float* wih1 = (const float*)d_in[5];
  const float* whh1 = (const float*)d_in[6];
  const float* bih1 = (const float*)d_in[7];
  const float* bhh1 = (const float*)d_in[8];
  const float* wih2 = (const float*)d_in[9];
  const float* whh2 = (const float*)d_in[10];
  const float* bih2 = (const float*)d_in[11];
  const float* bhh2 = (const float*)d_in[12];
  const float* fcw  = (const float*)d_in[13];
  const float* fcb  = (const float*)d_in[14];
  float* out = (float*)d_out;

  (void)hipFuncSetAttribute((const void*)rnn_pipe,
                            hipFuncAttributeMaxDynamicSharedMemorySize, (int)SM_BYTES);

  rnn_pipe<<<B_ / BT, NT, SM_BYTES, stream>>>(x,
      wih0, whh0, bih0, bhh0,
      wih1, whh1, bih1, bhh1,
      wih2, whh2, bih2, bhh2,
      fcw, fcb, out);
}